// Round 3
// baseline (60481.958 us; speedup 1.0000x reference)
//
#include <hip/hip_runtime.h>
#include <hip/hip_fp16.h>

#define EMB    1024
#define HID    2048
#define VOCAB  50257
#define T      256
#define NBLK   1024          // cooperative grid: 4 blocks/CU on 256 CUs
#define TPB    256
#define GW     (NBLK * 4)    // 4096 waves
#define NEG_INF (-3.402823466e38f)
#define IMAX    0x7fffffff

#define WF16_ELEMS ((size_t)VOCAB * HID)                 // 102,926,336
#define WF16_BYTES (WF16_ELEMS * 2)                      // 205,852,672 (16B aligned)

// small region layout (float-word offsets from smallBase):
//  hA:0  hB:2048  c:4096  bmv:6144(2048)  bmi:8192(2048)
//  grp:10240 (2T*32=16384 u32)  root:26624 (2T=512 u32)   total 27136 words
#define SMALL_WORDS 27136

__global__ void k_zero(float* p, int n) {
    for (int i = blockIdx.x * blockDim.x + threadIdx.x; i < n; i += gridDim.x * blockDim.x)
        p[i] = 0.0f;
}

__global__ void k_cvt(const float* __restrict__ src, __half2* __restrict__ dst, long n4) {
    for (long i = blockIdx.x * blockDim.x + threadIdx.x; i < n4; i += (long)gridDim.x * blockDim.x) {
        float4 v = *(const float4*)(src + i * 4);
        union { __half2 h[2]; float2 f; } u;
        u.h[0] = __floats2half2_rn(v.x, v.y);
        u.h[1] = __floats2half2_rn(v.z, v.w);
        *(float2*)((char*)dst + i * 8) = u.f;
    }
}

__device__ __forceinline__ void ins3(float v, int ix,
                                     float& v0, int& i0, float& v1, int& i1, float& v2, int& i2) {
    if (v > v0 || (v == v0 && ix < i0)) { v2 = v1; i2 = i1; v1 = v0; i1 = i0; v0 = v; i0 = ix; }
    else if (v > v1 || (v == v1 && ix < i1)) { v2 = v1; i2 = i1; v1 = v; i1 = ix; }
    else if (v > v2 || (v == v2 && ix < i2)) { v2 = v; i2 = ix; }
}

__device__ __forceinline__ void grid_barrier(unsigned* grp, unsigned* root, int slot) {
    __syncthreads();                       // all block waves arrived; vmem drained (vmcnt0 before s_barrier)
    if (threadIdx.x == 0) {
        __threadfence();                   // release: XCD L2 writeback
        unsigned g = (unsigned)blockIdx.x >> 5;      // 32 groups x 32 blocks
        unsigned p = atomicAdd(&grp[(size_t)slot * 32 + g], 1u);
        if (p == 31u) atomicAdd(&root[slot], 1u);
        while (__hip_atomic_load(&root[slot], __ATOMIC_RELAXED, __HIP_MEMORY_SCOPE_AGENT) < 32u)
            __builtin_amdgcn_s_sleep(2);
        __threadfence();                   // acquire: L1/L2 invalidate
    }
    __syncthreads();
}

__global__ __launch_bounds__(TPB, 4) void lstm_all(
    const float* __restrict__ emb,  const float* __restrict__ W_ih,
    const float* __restrict__ W_hh, const float* __restrict__ b_ih,
    const float* __restrict__ b_hh, const float* __restrict__ W_out,
    const float* __restrict__ b_out, float* __restrict__ out,
    const __half2* __restrict__ Wf16,
    float* hA, float* hB, float* c,
    float* bmv, int* bmi, unsigned* grp, unsigned* root, int useF16)
{
    __shared__ float xs[EMB];
    __shared__ float hs[HID];
    __shared__ float gvs[8];
    __shared__ float wtv[12];  __shared__ int wti[12];
    __shared__ float l2v[8];   __shared__ int l2i[8];
    __shared__ float cand_v[3]; __shared__ int cand_i[3];
    __shared__ int   tok_s;

    const int tid  = threadIdx.x;
    const int wave = tid >> 6;
    const int lane = tid & 63;

    for (int t = 0; t < T; ++t) {
        float* h_in  = (t & 1) ? hB : hA;
        float* h_out = (t & 1) ? hA : hB;

        // ---- prologue: stage h_in -> hs; compute tok (argmax of prev logits) ----
        for (int i = tid; i < HID / 4; i += TPB)
            ((float4*)hs)[i] = ((const float4*)h_in)[i];

        if (t == 0) {
            if (tid == 0) tok_s = 0;
            __syncthreads();
        } else {
            float v0 = NEG_INF, v1 = NEG_INF, v2 = NEG_INF;
            int   i0 = IMAX,    i1 = IMAX,    i2 = IMAX;
            for (int e = tid; e < 2 * NBLK; e += TPB)
                ins3(bmv[e], bmi[e], v0, i0, v1, i1, v2, i2);
            for (int off = 32; off; off >>= 1) {
                float a0 = __shfl_down(v0, off), a1 = __shfl_down(v1, off), a2 = __shfl_down(v2, off);
                int   b0 = __shfl_down(i0, off), b1 = __shfl_down(i1, off), b2 = __shfl_down(i2, off);
                ins3(a0, b0, v0, i0, v1, i1, v2, i2);
                ins3(a1, b1, v0, i0, v1, i1, v2, i2);
                ins3(a2, b2, v0, i0, v1, i1, v2, i2);
            }
            if (lane == 0) {
                wtv[wave * 3] = v0;     wti[wave * 3] = i0;
                wtv[wave * 3 + 1] = v1; wti[wave * 3 + 1] = i1;
                wtv[wave * 3 + 2] = v2; wti[wave * 3 + 2] = i2;
            }
            __syncthreads();                       // wtv ready; hs ready
            if (tid == 0) {
                float u0 = NEG_INF, u1 = NEG_INF, u2 = NEG_INF;
                int   j0 = IMAX,    j1 = IMAX,    j2 = IMAX;
                for (int e = 0; e < 12; ++e) ins3(wtv[e], wti[e], u0, j0, u1, j1, u2, j2);
                cand_i[0] = j0; cand_i[1] = j1; cand_i[2] = j2;
            }
            __syncthreads();
            if (wave < 3) {                        // exact f32 rescore of top-3 candidates
                int r = cand_i[wave];
                const float* w = W_out + (size_t)r * HID;
                float acc = 0.0f;
                #pragma unroll
                for (int it = 0; it < 8; ++it) {
                    int col = it * 256 + lane * 4;
                    float4 w4 = *(const float4*)(w + col);
                    float4 h4 = *(const float4*)(hs + col);
                    acc += w4.x * h4.x + w4.y * h4.y + w4.z * h4.z + w4.w * h4.w;
                }
                for (int off = 32; off; off >>= 1) acc += __shfl_down(acc, off);
                if (lane == 0) cand_v[wave] = acc + b_out[r];
            }
            __syncthreads();
            if (tid == 0) {
                float bv = cand_v[0]; int bi = cand_i[0];
                for (int k = 1; k < 3; ++k)
                    if (cand_v[k] > bv || (cand_v[k] == bv && cand_i[k] < bi)) { bv = cand_v[k]; bi = cand_i[k]; }
                tok_s = bi;
            }
            __syncthreads();
        }

        // ---- stage x = emb[tok] ----
        {
            const float* xrow = emb + (size_t)tok_s * EMB;
            for (int i = tid; i < EMB / 4; i += TPB)
                ((float4*)xs)[i] = ((const float4*)xrow)[i];
        }
        __syncthreads();

        // ---- phase G: 8192 gate rows, 2 rows/wave (f32) ----
        {
            int u  = wave & 1;
            int j  = blockIdx.x * 2 + u;
            int g0 = (wave >> 1) * 2;
            int r0 = g0 * HID + j, r1 = (g0 + 1) * HID + j;
            const float* wi0 = W_ih + (size_t)r0 * EMB;
            const float* wi1 = W_ih + (size_t)r1 * EMB;
            const float* wh0 = W_hh + (size_t)r0 * HID;
            const float* wh1 = W_hh + (size_t)r1 * HID;
            float a0 = 0.0f, a1 = 0.0f;
            #pragma unroll
            for (int it = 0; it < 4; ++it) {
                int col = it * 256 + lane * 4;
                float4 x4 = *(const float4*)(xs + col);
                float4 w4 = *(const float4*)(wi0 + col);
                float4 v4 = *(const float4*)(wi1 + col);
                a0 += w4.x * x4.x + w4.y * x4.y + w4.z * x4.z + w4.w * x4.w;
                a1 += v4.x * x4.x + v4.y * x4.y + v4.z * x4.z + v4.w * x4.w;
            }
            #pragma unroll
            for (int it = 0; it < 8; ++it) {
                int col = it * 256 + lane * 4;
                float4 h4 = *(const float4*)(hs + col);
                float4 w4 = *(const float4*)(wh0 + col);
                float4 v4 = *(const float4*)(wh1 + col);
                a0 += w4.x * h4.x + w4.y * h4.y + w4.z * h4.z + w4.w * h4.w;
                a1 += v4.x * h4.x + v4.y * h4.y + v4.z * h4.z + v4.w * h4.w;
            }
            for (int off = 32; off; off >>= 1) { a0 += __shfl_down(a0, off); a1 += __shfl_down(a1, off); }
            if (lane == 0) {
                gvs[u * 4 + g0]     = a0 + b_ih[r0] + b_hh[r0];
                gvs[u * 4 + g0 + 1] = a1 + b_ih[r1] + b_hh[r1];
            }
        }
        __syncthreads();
        if (tid < 2) {
            int j = blockIdx.x * 2 + tid;
            float gi = gvs[tid * 4 + 0], gf = gvs[tid * 4 + 1];
            float gg = gvs[tid * 4 + 2], go = gvs[tid * 4 + 3];
            float iv = 1.0f / (1.0f + expf(-gi));
            float fv = 1.0f / (1.0f + expf(-gf));
            float gt = tanhf(gg);
            float ov = 1.0f / (1.0f + expf(-go));
            float cn = fv * c[j] + iv * gt;
            c[j] = cn;
            h_out[j] = ov * tanhf(cn);
        }
        grid_barrier(grp, root, 2 * t);

        // ---- phase L: 50257 logit rows over 4096 waves ----
        {
            float4 hr[8];
            if (useF16) {
                #pragma unroll
                for (int i = 0; i < 4; ++i) {
                    int cb = (i * 64 + lane) * 8;
                    hr[2 * i]     = *(const float4*)(h_out + cb);
                    hr[2 * i + 1] = *(const float4*)(h_out + cb + 4);
                }
            } else {
                #pragma unroll
                for (int i = 0; i < 8; ++i)
                    hr[i] = *(const float4*)(h_out + (i * 64 + lane) * 4);
            }
            float* orow = out + (size_t)t * VOCAB;
            float tv0 = NEG_INF, tv1 = NEG_INF; int ti0 = IMAX, ti1 = IMAX;
            int Wg = blockIdx.x * 4 + wave;
            for (int r = Wg; r < VOCAB; r += GW) {
                float acc = 0.0f;
                if (useF16) {
                    const __half2* wr = Wf16 + (size_t)r * (HID / 2);
                    #pragma unroll
                    for (int i = 0; i < 4; ++i) {
                        float4 raw = *(const float4*)(wr + (i * 64 + lane) * 4);
                        union { float f; __half2 h; } u0, u1, u2, u3;
                        u0.f = raw.x; u1.f = raw.y; u2.f = raw.z; u3.f = raw.w;
                        float2 f0 = __half22float2(u0.h), f1 = __half22float2(u1.h);
                        float2 f2 = __half22float2(u2.h), f3 = __half22float2(u3.h);
                        float4 ha = hr[2 * i], hb = hr[2 * i + 1];
                        acc += f0.x * ha.x + f0.y * ha.y + f1.x * ha.z + f1.y * ha.w
                             + f2.x * hb.x + f2.y * hb.y + f3.x * hb.z + f3.y * hb.w;
                    }
                } else {
                    const float* wr = W_out + (size_t)r * HID;
                    #pragma unroll
                    for (int i = 0; i < 8; ++i) {
                        float4 w4 = *(const float4*)(wr + (i * 64 + lane) * 4);
                        float4 ha = hr[i];
                        acc += w4.x * ha.x + w4.y * ha.y + w4.z * ha.z + w4.w * ha.w;
                    }
                }
                for (int off = 32; off; off >>= 1) acc += __shfl_down(acc, off);
                if (lane == 0) {
                    float v = acc + b_out[r];
                    orow[r] = v;
                    if (v > tv0) { tv1 = tv0; ti1 = ti0; tv0 = v; ti0 = r; }
                    else if (v > tv1) { tv1 = v; ti1 = r; }
                }
            }
            if (lane == 0) {
                l2v[wave * 2] = tv0;     l2i[wave * 2] = ti0;
                l2v[wave * 2 + 1] = tv1; l2i[wave * 2 + 1] = ti1;
            }
        }
        __syncthreads();
        if (tid == 0) {
            float v0 = NEG_INF, v1 = NEG_INF; int i0 = IMAX, i1 = IMAX;
            for (int e = 0; e < 8; ++e) {
                float v = l2v[e]; int ix = l2i[e];
                if (v > v0 || (v == v0 && ix < i0)) { v1 = v0; i1 = i0; v0 = v; i0 = ix; }
                else if (v > v1 || (v == v1 && ix < i1)) { v1 = v; i1 = ix; }
            }
            bmv[2 * blockIdx.x] = v0;     bmi[2 * blockIdx.x] = i0;
            bmv[2 * blockIdx.x + 1] = v1; bmi[2 * blockIdx.x + 1] = i1;
        }
        grid_barrier(grp, root, 2 * t + 1);
    }
}

extern "C" void kernel_launch(void* const* d_in, const int* in_sizes, int n_in,
                              void* d_out, int out_size, void* d_ws, size_t ws_size,
                              hipStream_t stream) {
    const float* emb   = (const float*)d_in[0];
    const float* W_ih  = (const float*)d_in[1];
    const float* W_hh  = (const float*)d_in[2];
    const float* b_ih  = (const float*)d_in[3];
    const float* b_hh  = (const float*)d_in[4];
    const float* W_out = (const float*)d_in[5];
    const float* b_out = (const float*)d_in[6];
    float* out = (float*)d_out;

    size_t need = WF16_BYTES + (size_t)SMALL_WORDS * 4;
    int useF16 = (ws_size >= need) ? 1 : 0;

    char* wsb = (char*)d_ws;
    __half2* Wf16      = (__half2*)wsb;
    float*   smallBase = (float*)(useF16 ? (wsb + WF16_BYTES) : wsb);
    float* hA  = smallBase;
    float* hB  = smallBase + 2048;
    float* c   = smallBase + 4096;
    float* bmv = smallBase + 6144;
    int*   bmi = (int*)(smallBase + 8192);
    unsigned* grp  = (unsigned*)(smallBase + 10240);
    unsigned* root = (unsigned*)(smallBase + 26624);

    k_zero<<<64, 256, 0, stream>>>(smallBase, SMALL_WORDS);
    if (useF16) {
        long n4 = (long)(WF16_ELEMS / 4);
        k_cvt<<<4096, 256, 0, stream>>>(W_out, Wf16, n4);
    }

    void* args[] = { (void*)&emb, (void*)&W_ih, (void*)&W_hh, (void*)&b_ih, (void*)&b_hh,
                     (void*)&W_out, (void*)&b_out, (void*)&out, (void*)&Wf16,
                     (void*)&hA, (void*)&hB, (void*)&c, (void*)&bmv, (void*)&bmi,
                     (void*)&grp, (void*)&root, (void*)&useF16 };
    hipError_t e = hipLaunchCooperativeKernel((void*)lstm_all, dim3(NBLK), dim3(TPB),
                                              args, 0, stream);
    if (e != hipSuccess) {
        // all 1024 blocks (4/CU by resources) are co-resident in practice; barrier still safe
        lstm_all<<<NBLK, TPB, 0, stream>>>(emb, W_ih, W_hh, b_ih, b_hh, W_out, b_out, out,
                                           Wf16, hA, hB, c, bmv, bmi, grp, root, useF16);
    }
}